// Round 4
// baseline (349.096 us; speedup 1.0000x reference)
//
#include <hip/hip_runtime.h>
#include <hip/hip_fp16.h>
#include <cstdint>
#include <cstddef>

#define B_ 4
#define S_ 4096
#define D_ 1024
#define E_ 1536
#define M_ (B_*S_)       // 16384
#define BE_ (B_*E_)      // 6144
#define C_ 32            // scan chunks
#define L_ (S_/C_)       // 128

typedef short bf16x8 __attribute__((ext_vector_type(8)));
typedef float f32x4 __attribute__((ext_vector_type(4)));

__device__ __forceinline__ unsigned short f2b(float f) {
  union { float f; unsigned int i; } x; x.f = f;
  unsigned int r = x.i + 0x7FFFu + ((x.i >> 16) & 1u);   // RNE
  return (unsigned short)(r >> 16);
}
__device__ __forceinline__ float h2f(unsigned short u) { return __half2float(__ushort_as_half(u)); }
__device__ __forceinline__ unsigned int packcv(float c, float v) {
  return (unsigned int)__half_as_ushort(__float2half_rn(c)) |
         ((unsigned int)__half_as_ushort(__float2half_rn(v)) << 16);
}
__device__ __forceinline__ void async16(const unsigned short* g, unsigned short* l) {
  __builtin_amdgcn_global_load_lds((const __attribute__((address_space(1))) unsigned int*)g,
                                   (__attribute__((address_space(3))) unsigned int*)l, 16, 0, 0);
}

// ---------- fp32 -> bf16 conversion, generic (1024 elems / block) ----------
__global__ __launch_bounds__(256) void cvt_bf16(const float* __restrict__ src,
                                                unsigned short* __restrict__ dst) {
  const int i = blockIdx.x * 256 + threadIdx.x;
  float4 f = ((const float4*)src)[i];
  ushort4 u; u.x = f2b(f.x); u.y = f2b(f.y); u.z = f2b(f.z); u.w = f2b(f.w);
  ((ushort4*)dst)[i] = u;
}

// ---------- fused conversion: x + W_hg (W_out must wait until CV is dead) ----------
#define NB_X   (M_*D_/1024)        // 16384 blocks
#define NB_WHG (2*E_*D_/1024)      // 3072
__global__ __launch_bounds__(256) void cvt_xw(const float* __restrict__ x, unsigned short* __restrict__ xb,
                                              const float* __restrict__ whg, unsigned short* __restrict__ wb) {
  int blk = blockIdx.x;
  const float* src; unsigned short* dst;
  if (blk < NB_X) { src = x; dst = xb; }
  else            { blk -= NB_X; src = whg; dst = wb; }
  const int i = blk * 256 + threadIdx.x;
  float4 f = ((const float4*)src)[i];
  ushort4 u; u.x = f2b(f.x); u.y = f2b(f.y); u.z = f2b(f.z); u.w = f2b(f.w);
  ((ushort4*)dst)[i] = u;
}

// ---------- GEMM1: 256m x 256n(=128h+128g) x BK=64, 8 waves, 4-phase counted-vmcnt pipeline ----------
// LDS: 2 buffers x (A[256][64] + B[256][64]) bf16 = 128 KB. Half-tiles = 128-row halves (16KB),
// staged as 16 chunks of 1KB (8 rows x 8 x 16B); wave wv stages chunks wv*2, wv*2+1 per half.
// T2 swizzle: global source 16B-col pre-permuted (scs = scol ^ srow; row&7==srow), ds_read
// XORs (lm&7) — proven conflict-free pair from rounds 1-3.
// Per K-tile t (4 phases), staging tile t+1 into the other buffer:
//   P1: vmcnt(2) ensures A0,A1,B0 of t landed (only B1(t) newer); barrier; stage A0(t+1);
//       ds_read af[0..3][kh], bn(h-half); MFMA mf0-3 x nf0-1.
//   P2: stage A1(t+1); ds_read af[4..7]; MFMA mf4-7 x nf0-1.
//   P3: vmcnt(4) ensures B1(t) landed (A0,A1 of t+1 newer); barrier; stage B0(t+1);
//       ds_read bn(g-half); MFMA mf0-3 x nf2-3.
//   P4: stage B1(t+1); MFMA mf4-7 x nf2-3.
// Wave wm owns A rows wm*128..+127 (one half-tile); wave wn owns e-cols wn*32..+31 with
// n-frags {h: rB=wn*32(+16), g: rB=128+wn*32(+16)} so gate pointwise stays in-register.
// Epilogue: gate+pack -> CV global + LDS; fused scan_p1 over 2 chunks x 128 e.
__global__ __launch_bounds__(512) void gemm1_mfma(const unsigned short* __restrict__ Xb,
                                                  const unsigned short* __restrict__ Wb,
                                                  unsigned int* __restrict__ CV,
                                                  float* __restrict__ Pd,
                                                  float* __restrict__ Qfd,
                                                  float* __restrict__ Qrd) {
  __shared__ unsigned short sm[65536];   // 128 KB: buf c at c*32768 (A at +0, B at +16384)
  const int t = threadIdx.x;
  const int m0 = blockIdx.x * 256;
  const int n0 = blockIdx.y * 128;
  const int wv = t >> 6, lane = t & 63;
  const int wm = wv >> 2, wn = wv & 3;       // wm: 128-m half; wn: 32-e column group
  const int lm = lane & 15, kg = lane >> 4;
  const int l7 = lm & 7;
  const int srow = lane >> 3;
  const int scs = (lane & 7) ^ srow;         // swizzled source 16B-column
  const int c0 = wv * 2;                     // this wave's chunk base within each half-tile

  // per-thread global offsets (ushort units) for staging chunk c0 of each half
  const int offA  = (m0 + c0 * 8 + srow) * D_ + scs * 8;        // A rows (half0; +128*D_ for half1)
  const int offB0 = (n0 + c0 * 8 + srow) * D_ + scs * 8;        // h rows
  const int offB1 = (E_ + n0 + c0 * 8 + srow) * D_ + scs * 8;   // g rows

  unsigned short* rdp = sm;          // compute buffer
  unsigned short* wrp = sm + 32768;  // staging buffer

  // prologue: stage tile 0 into buf0 — issue order A0, A1, B0, B1 (vmcnt accounting)
  async16(Xb + offA,           rdp + c0 * 512);
  async16(Xb + offA + 8 * D_,  rdp + c0 * 512 + 512);
  async16(Xb + offA + 128 * D_, rdp + 8192 + c0 * 512);
  async16(Xb + offA + 136 * D_, rdp + 8192 + c0 * 512 + 512);
  async16(Wb + offB0,          rdp + 16384 + c0 * 512);
  async16(Wb + offB0 + 8 * D_, rdp + 16384 + c0 * 512 + 512);
  async16(Wb + offB1,          rdp + 24576 + c0 * 512);
  async16(Wb + offB1 + 8 * D_, rdp + 24576 + c0 * 512 + 512);

  const f32x4 z4 = {0.f, 0.f, 0.f, 0.f};
  f32x4 acc[8][4];
#pragma unroll
  for (int i = 0; i < 8; ++i)
#pragma unroll
    for (int j = 0; j < 4; ++j) acc[i][j] = z4;

  bf16x8 af[8][2], bn[2][2];
  const int NT = D_ / 64;   // 16
  for (int kt = 0; kt < NT; ++kt) {
    const int k2 = (kt + 1) * 64;
    const bool st = (kt + 1 < NT);
    // ---------------- P1 ----------------
    asm volatile("s_waitcnt vmcnt(2)" ::: "memory");
    asm volatile("s_barrier" ::: "memory");
    __builtin_amdgcn_sched_barrier(0);
    if (st) {
      async16(Xb + offA + k2,          wrp + c0 * 512);
      async16(Xb + offA + 8 * D_ + k2, wrp + c0 * 512 + 512);
    }
#pragma unroll
    for (int mf = 0; mf < 4; ++mf)
#pragma unroll
      for (int kh = 0; kh < 2; ++kh)
        af[mf][kh] = *(const bf16x8*)(rdp + (size_t)(wm * 128 + mf * 16 + lm) * 64 +
                                      ((((kh << 2) | kg) ^ l7) << 3));
#pragma unroll
    for (int j = 0; j < 2; ++j)
#pragma unroll
      for (int kh = 0; kh < 2; ++kh)
        bn[j][kh] = *(const bf16x8*)(rdp + 16384 + (size_t)(wn * 32 + j * 16 + lm) * 64 +
                                     ((((kh << 2) | kg) ^ l7) << 3));
    __builtin_amdgcn_s_setprio(1);
#pragma unroll
    for (int mf = 0; mf < 4; ++mf)
#pragma unroll
      for (int j = 0; j < 2; ++j)
#pragma unroll
        for (int kh = 0; kh < 2; ++kh)
          acc[mf][j] = __builtin_amdgcn_mfma_f32_16x16x32_bf16(af[mf][kh], bn[j][kh], acc[mf][j], 0, 0, 0);
    __builtin_amdgcn_s_setprio(0);
    // ---------------- P2 ----------------
    if (st) {
      async16(Xb + offA + 128 * D_ + k2, wrp + 8192 + c0 * 512);
      async16(Xb + offA + 136 * D_ + k2, wrp + 8192 + c0 * 512 + 512);
    }
#pragma unroll
    for (int mf = 4; mf < 8; ++mf)
#pragma unroll
      for (int kh = 0; kh < 2; ++kh)
        af[mf][kh] = *(const bf16x8*)(rdp + (size_t)(wm * 128 + mf * 16 + lm) * 64 +
                                      ((((kh << 2) | kg) ^ l7) << 3));
    __builtin_amdgcn_s_setprio(1);
#pragma unroll
    for (int mf = 4; mf < 8; ++mf)
#pragma unroll
      for (int j = 0; j < 2; ++j)
#pragma unroll
        for (int kh = 0; kh < 2; ++kh)
          acc[mf][j] = __builtin_amdgcn_mfma_f32_16x16x32_bf16(af[mf][kh], bn[j][kh], acc[mf][j], 0, 0, 0);
    __builtin_amdgcn_s_setprio(0);
    // ---------------- P3 ----------------
    if (kt < NT - 1) asm volatile("s_waitcnt vmcnt(4)" ::: "memory");
    else             asm volatile("s_waitcnt vmcnt(0)" ::: "memory");
    asm volatile("s_barrier" ::: "memory");
    __builtin_amdgcn_sched_barrier(0);
    if (st) {
      async16(Wb + offB0 + k2,          wrp + 16384 + c0 * 512);
      async16(Wb + offB0 + 8 * D_ + k2, wrp + 16384 + c0 * 512 + 512);
    }
#pragma unroll
    for (int j = 0; j < 2; ++j)
#pragma unroll
      for (int kh = 0; kh < 2; ++kh)
        bn[j][kh] = *(const bf16x8*)(rdp + 16384 + (size_t)(128 + wn * 32 + j * 16 + lm) * 64 +
                                     ((((kh << 2) | kg) ^ l7) << 3));
    __builtin_amdgcn_s_setprio(1);
#pragma unroll
    for (int mf = 0; mf < 4; ++mf)
#pragma unroll
      for (int j = 0; j < 2; ++j)
#pragma unroll
        for (int kh = 0; kh < 2; ++kh)
          acc[mf][j + 2] = __builtin_amdgcn_mfma_f32_16x16x32_bf16(af[mf][kh], bn[j][kh], acc[mf][j + 2], 0, 0, 0);
    __builtin_amdgcn_s_setprio(0);
    // ---------------- P4 ----------------
    if (st) {
      async16(Wb + offB1 + k2,          wrp + 24576 + c0 * 512);
      async16(Wb + offB1 + 8 * D_ + k2, wrp + 24576 + c0 * 512 + 512);
    }
    __builtin_amdgcn_s_setprio(1);
#pragma unroll
    for (int mf = 4; mf < 8; ++mf)
#pragma unroll
      for (int j = 0; j < 2; ++j)
#pragma unroll
        for (int kh = 0; kh < 2; ++kh)
          acc[mf][j + 2] = __builtin_amdgcn_mfma_f32_16x16x32_bf16(af[mf][kh], bn[j][kh], acc[mf][j + 2], 0, 0, 0);
    __builtin_amdgcn_s_setprio(0);
    unsigned short* tp = rdp; rdp = wrp; wrp = tp;
  }

  __syncthreads();                            // all waves done with LDS; free for reuse
  // epilogue: gate pointwise + pack; store CV global; stage packed into LDS [256m][128e]
  unsigned int* sc = (unsigned int*)sm;       // 128 KB
#pragma unroll
  for (int mf = 0; mf < 8; ++mf)
#pragma unroll
    for (int p = 0; p < 2; ++p) {
      const int eloc = wn * 32 + p * 16 + lm;
      const int e = n0 + eloc;
#pragma unroll
      for (int r = 0; r < 4; ++r) {
        const int mloc = wm * 128 + mf * 16 + kg * 4 + r;
        const float hid = acc[mf][p][r];
        const float gat = acc[mf][p + 2][r];
        const float z = 1.f / (1.f + __expf(-gat));
        const float cc = 1.f - z;
        const float gv = (hid >= 0.f) ? (hid + 0.5f) : (1.f / (1.f + __expf(-hid)));
        const unsigned int pk = packcv(cc, z * gv);
        CV[(size_t)(m0 + mloc) * E_ + e] = pk;
        sc[mloc * 128 + eloc] = pk;
      }
    }
  __syncthreads();
  // fused scan_p1: 2 chunks of 128 m; 4 segments of 32 m each; thread -> e = t&127, seg = t>>7
  const int er = t & 127, seg = t >> 7;
  float rp[2][3];
#pragma unroll
  for (int c = 0; c < 2; ++c) {
    float pp = 1.f, qf = 0.f, qr = 0.f;
#pragma unroll 8
    for (int l = 0; l < 32; ++l) {
      const unsigned int p = sc[(c * 128 + seg * 32 + l) * 128 + er];
      const float cv = h2f((unsigned short)p), vv = h2f((unsigned short)(p >> 16));
      qf = fmaf(cv, qf, vv);
      qr = fmaf(pp, vv, qr);
      pp *= cv;
    }
    rp[c][0] = pp; rp[c][1] = qf; rp[c][2] = qr;
  }
  __syncthreads();                            // all sc reads done before overwrite
  float* red = (float*)sm;                    // 2 chunks x 4 segs x 128 e x 3 = 12 KB
#pragma unroll
  for (int c = 0; c < 2; ++c) {
    red[c * 1536 + (seg * 128 + er) * 3 + 0] = rp[c][0];
    red[c * 1536 + (seg * 128 + er) * 3 + 1] = rp[c][1];
    red[c * 1536 + (seg * 128 + er) * 3 + 2] = rp[c][2];
  }
  __syncthreads();
  if (t < 256) {                              // chunk c = t>>7, e = t&127
    const int c = t >> 7, e = t & 127;
    float Pv = 1.f, Qfv = 0.f, Qrv = 0.f;
#pragma unroll
    for (int s = 0; s < 4; ++s) {
      const float ps  = red[c * 1536 + (s * 128 + e) * 3 + 0];
      const float qfs = red[c * 1536 + (s * 128 + e) * 3 + 1];
      const float qrs = red[c * 1536 + (s * 128 + e) * 3 + 2];
      Qfv = fmaf(ps, Qfv, qfs);
      Qrv = fmaf(Pv, qrs, Qrv);
      Pv *= ps;
    }
    const int kk = ((m0 & (S_ - 1)) >> 7) + c;
    const int be = (m0 >> 12) * E_ + n0 + e;
    Pd [(size_t)kk * BE_ + be] = Pv;
    Qfd[(size_t)kk * BE_ + be] = Qfv;
    Qrd[(size_t)kk * BE_ + be] = Qrv;
  }
}

// ---------- scan pass 2: chunk-level prefix (preloaded, fully unrolled) ----------
__global__ __launch_bounds__(256) void scan_p2(const float* __restrict__ P, const float* __restrict__ Qf,
                                               const float* __restrict__ Qr, float* __restrict__ HfIn,
                                               float* __restrict__ HbIn) {
  const int be = blockIdx.x * 256 + threadIdx.x;
  float Pk[C_], Qk[C_];
#pragma unroll
  for (int k = 0; k < C_; ++k) { Pk[k] = P[(size_t)k * BE_ + be]; Qk[k] = Qf[(size_t)k * BE_ + be]; }
  float hf = 0.f;
#pragma unroll
  for (int k = 0; k < C_; ++k) {
    HfIn[(size_t)k * BE_ + be] = hf;
    hf = fmaf(Pk[k], hf, Qk[k]);
  }
#pragma unroll
  for (int k = 0; k < C_; ++k) Qk[k] = Qr[(size_t)k * BE_ + be];
  float hb = 0.f;
#pragma unroll
  for (int k = C_ - 1; k >= 0; --k) {
    HbIn[(size_t)k * BE_ + be] = hb;   // state after consuming original chunks > k
    hb = fmaf(Pk[k], hb, Qk[k]);
  }
}

// ---------- scan pass 3: replay with carry-ins, write H = hf + hb (bf16) ----------
__global__ __launch_bounds__(256) void scan_p3(const unsigned int* __restrict__ CV,
                                               const float* __restrict__ HfIn,
                                               const float* __restrict__ HbIn,
                                               unsigned short* __restrict__ Hb) {
  const int be = blockIdx.x * 256 + threadIdx.x;
  const int b = be / E_, e = be - b * E_;
  const int k = blockIdx.y;
  const unsigned int* cvf = CV + ((size_t)b * S_ + (size_t)k * L_) * E_ + e;
  const unsigned int* cvb = CV + ((size_t)b * S_ + (size_t)(S_ - 1 - k * L_)) * E_ + e;
  unsigned short* hp = Hb + ((size_t)b * S_ + (size_t)k * L_) * E_ + e;
  float hf = HfIn[(size_t)k * BE_ + be];
  float hb = HbIn[(size_t)(C_ - 1 - k) * BE_ + be];
#pragma unroll 8
  for (int l = 0; l < L_; ++l) {
    const unsigned int pf = cvf[(size_t)l * E_];
    const unsigned int pb = *(cvb - (ptrdiff_t)l * E_);
    hf = fmaf(h2f((unsigned short)pf), hf, h2f((unsigned short)(pf >> 16)));
    hb = fmaf(h2f((unsigned short)pb), hb, h2f((unsigned short)(pb >> 16)));
    hp[(size_t)l * E_] = f2b(hf + hb);
  }
}

// ---------- GEMM2 (proven structure: 256 thr, BK=64, async staging, T2 swizzle) ----------
// out[m,d] = sum_e H[m,e]*Wo[d,e].  tile 128m x 128d; 4 waves each 64m x 64d.
__global__ __launch_bounds__(256) void gemm2_mfma(const unsigned short* __restrict__ Hb,
                                                  const unsigned short* __restrict__ Wob,
                                                  float* __restrict__ Out) {
  __shared__ unsigned short lA[128 * 64];   // 16KB
  __shared__ unsigned short lB[128 * 64];   // 16KB
  const int t = threadIdx.x;
  const int m0 = blockIdx.x * 128;
  const int n0 = blockIdx.y * 128;
  const int wv = t >> 6, lane = t & 63;
  const int wm = wv >> 1, wn = wv & 1;
  const int lm = lane & 15, kg = lane >> 4;
  const int srow = lane >> 3;
  const int scs = (lane & 7) ^ srow;        // swizzled source 16B-column
  const bool stageA = (wv < 2);
  const unsigned short* gbase;
  if (stageA) gbase = Hb  + (size_t)(m0 + wv * 64 + srow) * E_ + scs * 8;
  else        gbase = Wob + (size_t)(n0 + (wv - 2) * 64 + srow) * E_ + scs * 8;
  unsigned short* lbase = (stageA ? lA : lB) + (size_t)(wv & 1) * 4096;

  const f32x4 z4 = {0.f, 0.f, 0.f, 0.f};
  f32x4 acc[4][4];
#pragma unroll
  for (int i = 0; i < 4; ++i)
#pragma unroll
    for (int j = 0; j < 4; ++j) acc[i][j] = z4;

  for (int k0 = 0; k0 < E_; k0 += 64) {
#pragma unroll
    for (int j = 0; j < 8; ++j)
      async16(gbase + k0 + (size_t)(j * 8) * E_, lbase + (size_t)j * 512);
    __syncthreads();
#pragma unroll
    for (int kh = 0; kh < 2; ++kh) {
      const int cb = ((((kh << 2) | kg) ^ (lm & 7)) << 3);   // swizzled col (ushort units)
      bf16x8 af[4], bfr[4];
#pragma unroll
      for (int mt = 0; mt < 4; ++mt)
        af[mt] = *(const bf16x8*)(lA + (size_t)(wm * 64 + mt * 16 + lm) * 64 + cb);
#pragma unroll
      for (int nt = 0; nt < 4; ++nt)
        bfr[nt] = *(const bf16x8*)(lB + (size_t)(wn * 64 + nt * 16 + lm) * 64 + cb);
#pragma unroll
      for (int mt = 0; mt < 4; ++mt)
#pragma unroll
        for (int nt = 0; nt < 4; ++nt)
          acc[mt][nt] = __builtin_amdgcn_mfma_f32_16x16x32_bf16(af[mt], bfr[nt], acc[mt][nt], 0, 0, 0);
    }
    __syncthreads();
  }
#pragma unroll
  for (int mt = 0; mt < 4; ++mt)
#pragma unroll
    for (int nt = 0; nt < 4; ++nt) {
      const int d = n0 + wn * 64 + nt * 16 + lm;
#pragma unroll
      for (int r = 0; r < 4; ++r) {
        const int m = m0 + wm * 64 + mt * 16 + kg * 4 + r;
        Out[(size_t)m * D_ + d] = acc[mt][nt][r];
      }
    }
}

extern "C" void kernel_launch(void* const* d_in, const int* in_sizes, int n_in,
                              void* d_out, int out_size, void* d_ws, size_t ws_size,
                              hipStream_t stream) {
  const float* x    = (const float*)d_in[0];
  const float* whg  = (const float*)d_in[1];
  const float* wout = (const float*)d_in[2];
  float* out = (float*)d_out;

  // ws (151 MB, proven-safe): [CV: M*E*4][H: M*E*2]
  unsigned int*  CV = (unsigned int*)d_ws;
  unsigned short* Hb = (unsigned short*)((char*)d_ws + (size_t)M_ * E_ * 4);
  unsigned short* Xb  = Hb;                     // bf16 X in H region until scan writes H
  unsigned short* Wb  = Xb + (size_t)M_ * D_;
  unsigned short* Wob = (unsigned short*)d_ws;  // bf16 W_out in CV region — ONLY after scans done
  // scan chunk scratch in d_out (gemm2 fully overwrites)
  float* P    = out;
  float* Qf   = out + (size_t)C_ * BE_;
  float* Qr   = out + 2 * (size_t)C_ * BE_;
  float* HfIn = out + 3 * (size_t)C_ * BE_;
  float* HbIn = out + 4 * (size_t)C_ * BE_;

  cvt_xw<<<NB_X + NB_WHG, 256, 0, stream>>>(x, Xb, whg, Wb);
  gemm1_mfma<<<dim3(M_ / 256, E_ / 128), 512, 0, stream>>>(Xb, Wb, CV, P, Qf, Qr);
  scan_p2<<<BE_ / 256, 256, 0, stream>>>(P, Qf, Qr, HfIn, HbIn);
  scan_p3<<<dim3(BE_ / 256, C_), 256, 0, stream>>>(CV, HfIn, HbIn, Hb);
  cvt_bf16<<<D_ * E_ / 1024, 256, 0, stream>>>(wout, Wob);   // CV dead now
  gemm2_mfma<<<dim3(M_ / 128, D_ / 128), 256, 0, stream>>>(Hb, Wob, out);
}

// Round 6
// 344.180 us; speedup vs baseline: 1.0143x; 1.0143x over previous
//
#include <hip/hip_runtime.h>
#include <hip/hip_fp16.h>
#include <cstdint>
#include <cstddef>

#define B_ 4
#define S_ 4096
#define D_ 1024
#define E_ 1536
#define M_ (B_*S_)       // 16384
#define BE_ (B_*E_)      // 6144
#define C_ 32            // scan chunks
#define L_ (S_/C_)       // 128

typedef short bf16x8 __attribute__((ext_vector_type(8)));
typedef float f32x4 __attribute__((ext_vector_type(4)));

__device__ __forceinline__ unsigned short f2b(float f) {
  union { float f; unsigned int i; } x; x.f = f;
  unsigned int r = x.i + 0x7FFFu + ((x.i >> 16) & 1u);   // RNE
  return (unsigned short)(r >> 16);
}
__device__ __forceinline__ float h2f(unsigned short u) { return __half2float(__ushort_as_half(u)); }
__device__ __forceinline__ unsigned int packcv(float c, float v) {
  return (unsigned int)__half_as_ushort(__float2half_rn(c)) |
         ((unsigned int)__half_as_ushort(__float2half_rn(v)) << 16);
}
__device__ __forceinline__ void async16(const unsigned short* g, unsigned short* l) {
  __builtin_amdgcn_global_load_lds((const __attribute__((address_space(1))) unsigned int*)g,
                                   (__attribute__((address_space(3))) unsigned int*)l, 16, 0, 0);
}

// ---------- fp32 -> bf16 conversion, generic (1024 elems / block) ----------
__global__ __launch_bounds__(256) void cvt_bf16(const float* __restrict__ src,
                                                unsigned short* __restrict__ dst) {
  const int i = blockIdx.x * 256 + threadIdx.x;
  float4 f = ((const float4*)src)[i];
  ushort4 u; u.x = f2b(f.x); u.y = f2b(f.y); u.z = f2b(f.z); u.w = f2b(f.w);
  ((ushort4*)dst)[i] = u;
}

// ---------- fused conversion: x + W_hg (W_out must wait until CV is dead) ----------
#define NB_X   (M_*D_/1024)        // 16384 blocks
#define NB_WHG (2*E_*D_/1024)      // 3072
__global__ __launch_bounds__(256) void cvt_xw(const float* __restrict__ x, unsigned short* __restrict__ xb,
                                              const float* __restrict__ whg, unsigned short* __restrict__ wb) {
  int blk = blockIdx.x;
  const float* src; unsigned short* dst;
  if (blk < NB_X) { src = x; dst = xb; }
  else            { blk -= NB_X; src = whg; dst = wb; }
  const int i = blk * 256 + threadIdx.x;
  float4 f = ((const float4*)src)[i];
  ushort4 u; u.x = f2b(f.x); u.y = f2b(f.y); u.z = f2b(f.z); u.w = f2b(f.w);
  ((ushort4*)dst)[i] = u;
}

// ---------- GEMM1 (proven 870 TF structure: 256 thr, 32KB LDS, 2-barrier loop, T2 swizzle)
// + fused gate pointwise + fused scan_p1 (validated rounds 2-3, identical numerics).
__global__ __launch_bounds__(256) void gemm1_mfma(const unsigned short* __restrict__ Xb,
                                                  const unsigned short* __restrict__ Wb,
                                                  unsigned int* __restrict__ CV,
                                                  float* __restrict__ Pd,
                                                  float* __restrict__ Qfd,
                                                  float* __restrict__ Qrd) {
  __shared__ unsigned short sm[2 * 128 * 64];   // 32KB total: lA = sm, lB = sm + 8192
  unsigned short* lA = sm;
  unsigned short* lB = sm + 8192;
  const int t = threadIdx.x;
  const int m0 = blockIdx.x * 128;
  const int n0 = blockIdx.y * 64;
  const int wv = t >> 6, lane = t & 63;
  const int wm = wv >> 1, we = wv & 1;
  const int lm = lane & 15, kg = lane >> 4;
  const int srow = lane >> 3;
  const int scs = (lane & 7) ^ srow;            // swizzled source 16B-column
  const bool stageA = (wv < 2);
  const unsigned short* gbase;
  if (stageA) {
    gbase = Xb + (size_t)(m0 + (wv * 64) + srow) * D_ + scs * 8;
  } else {
    const int rloc = (wv - 2) * 64 + srow;      // 0..7 -> h rows, 64..71 -> g rows
    const int gr = (rloc < 64) ? (n0 + rloc) : (E_ + n0 + rloc - 64);
    gbase = Wb + (size_t)gr * D_ + scs * 8;
  }
  unsigned short* lbase = (stageA ? lA : lB) + (size_t)(wv & 1) * 4096;

  const f32x4 z4 = {0.f, 0.f, 0.f, 0.f};
  f32x4 ah[4][2], ag[4][2];
#pragma unroll
  for (int i = 0; i < 4; ++i)
#pragma unroll
    for (int j = 0; j < 2; ++j) { ah[i][j] = z4; ag[i][j] = z4; }

  for (int k0 = 0; k0 < D_; k0 += 64) {
#pragma unroll
    for (int j = 0; j < 8; ++j)
      async16(gbase + k0 + (size_t)(j * 8) * D_, lbase + (size_t)j * 512);
    __syncthreads();
#pragma unroll
    for (int kh = 0; kh < 2; ++kh) {
      const int cb = ((((kh << 2) | kg) ^ (lm & 7)) << 3);   // swizzled col (ushort units)
      bf16x8 af[4], bh[2], bg[2];
#pragma unroll
      for (int mt = 0; mt < 4; ++mt)
        af[mt] = *(const bf16x8*)(lA + (size_t)(wm * 64 + mt * 16 + lm) * 64 + cb);
#pragma unroll
      for (int et = 0; et < 2; ++et) {
        bh[et] = *(const bf16x8*)(lB + (size_t)(we * 32 + et * 16 + lm) * 64 + cb);
        bg[et] = *(const bf16x8*)(lB + (size_t)(64 + we * 32 + et * 16 + lm) * 64 + cb);
      }
#pragma unroll
      for (int mt = 0; mt < 4; ++mt)
#pragma unroll
        for (int et = 0; et < 2; ++et) {
          ah[mt][et] = __builtin_amdgcn_mfma_f32_16x16x32_bf16(af[mt], bh[et], ah[mt][et], 0, 0, 0);
          ag[mt][et] = __builtin_amdgcn_mfma_f32_16x16x32_bf16(af[mt], bg[et], ag[mt][et], 0, 0, 0);
        }
    }
    __syncthreads();
  }

  // epilogue: pointwise gate + pack; store CV; stage packed into LDS [128m][64e]
  unsigned int* sc = (unsigned int*)sm;         // 32KB, exactly lA+lB
#pragma unroll
  for (int mt = 0; mt < 4; ++mt)
#pragma unroll
    for (int et = 0; et < 2; ++et) {
      const int eloc = we * 32 + et * 16 + lm;
      const int e = n0 + eloc;
#pragma unroll
      for (int r = 0; r < 4; ++r) {
        const int mloc = wm * 64 + mt * 16 + kg * 4 + r;
        const float hid = ah[mt][et][r];
        const float gat = ag[mt][et][r];
        const float z = 1.f / (1.f + __expf(-gat));
        const float cc = 1.f - z;
        const float gv = (hid >= 0.f) ? (hid + 0.5f) : (1.f / (1.f + __expf(-hid)));
        const unsigned int pk = packcv(cc, z * gv);
        CV[(size_t)(m0 + mloc) * E_ + e] = pk;
        sc[mloc * 64 + eloc] = pk;
      }
    }
  __syncthreads();
  // fused scan_p1: 4 segments of 32 m; thread -> e = t&63, seg = t>>6
  const int er = t & 63, seg = t >> 6;
  float pp = 1.f, qf = 0.f, qr = 0.f;
#pragma unroll 8
  for (int l = 0; l < 32; ++l) {
    const unsigned int p = sc[(seg * 32 + l) * 64 + er];
    const float c = h2f((unsigned short)p), v = h2f((unsigned short)(p >> 16));
    qf = fmaf(c, qf, v);
    qr = fmaf(pp, v, qr);
    pp *= c;
  }
  __syncthreads();                              // all sc reads done before overwrite
  float* red = (float*)sm;                      // 4 segs x 64 e x 3 floats = 3KB
  red[(seg * 64 + er) * 3 + 0] = pp;
  red[(seg * 64 + er) * 3 + 1] = qf;
  red[(seg * 64 + er) * 3 + 2] = qr;
  __syncthreads();
  if (t < 64) {                                 // one chunk per block; e = t
    const int e = t;
    float Pv = 1.f, Qfv = 0.f, Qrv = 0.f;
#pragma unroll
    for (int s = 0; s < 4; ++s) {
      const float ps  = red[(s * 64 + e) * 3 + 0];
      const float qfs = red[(s * 64 + e) * 3 + 1];
      const float qrs = red[(s * 64 + e) * 3 + 2];
      Qfv = fmaf(ps, Qfv, qfs);
      Qrv = fmaf(Pv, qrs, Qrv);
      Pv *= ps;
    }
    const int kk = (m0 & (S_ - 1)) >> 7;        // chunk index within batch
    const int be = (m0 >> 12) * E_ + n0 + e;    // b*E_ + e
    Pd [(size_t)kk * BE_ + be] = Pv;
    Qfd[(size_t)kk * BE_ + be] = Qfv;
    Qrd[(size_t)kk * BE_ + be] = Qrv;
  }
}

// ---------- scan pass 2: chunk-level prefix (preloaded, fully unrolled) ----------
__global__ __launch_bounds__(256) void scan_p2(const float* __restrict__ P, const float* __restrict__ Qf,
                                               const float* __restrict__ Qr, float* __restrict__ HfIn,
                                               float* __restrict__ HbIn) {
  const int be = blockIdx.x * 256 + threadIdx.x;
  float Pk[C_], Qk[C_];
#pragma unroll
  for (int k = 0; k < C_; ++k) { Pk[k] = P[(size_t)k * BE_ + be]; Qk[k] = Qf[(size_t)k * BE_ + be]; }
  float hf = 0.f;
#pragma unroll
  for (int k = 0; k < C_; ++k) {
    HfIn[(size_t)k * BE_ + be] = hf;
    hf = fmaf(Pk[k], hf, Qk[k]);
  }
#pragma unroll
  for (int k = 0; k < C_; ++k) Qk[k] = Qr[(size_t)k * BE_ + be];
  float hb = 0.f;
#pragma unroll
  for (int k = C_ - 1; k >= 0; --k) {
    HbIn[(size_t)k * BE_ + be] = hb;   // state after consuming original chunks > k
    hb = fmaf(Pk[k], hb, Qk[k]);
  }
}

// ---------- scan pass 3 v2 (fixed): paired chunks, CV read ONCE, LDS-staged ----------
// Block (x = 64-col be-slice, y = pair kp): wave wv stages chunk (wv ? C-1-k : k) slice
// [128 rows][64 uints] into its LDS half with a WAVE-UNIFORM base (smU + wv*8192 uints);
// per issue j the wave covers rows j*4+(lane>>4), cols (lane&15)*4 — which matches the
// hardware's automatic lane*16B LDS placement ((lane>>4)*128+(lane&15)*8 == lane*8 ushorts).
// Then wave wv emits output chunk ck: forward over its own chunk ascending (carry HfIn[ck])
// + backward over the partner chunk descending (carry HbIn[C-1-ck]). Same FMA sequence on
// the same bits as the original -> bit-identical H. CV HBM read halves (200 -> 100 MB).
__global__ __launch_bounds__(128) void scan_p3(const unsigned int* __restrict__ CV,
                                               const float* __restrict__ HfIn,
                                               const float* __restrict__ HbIn,
                                               unsigned short* __restrict__ Hb) {
  __shared__ unsigned int smU[2 * 128 * 64];   // 64KB: wave0's chunk at 0, wave1's at +8192
  const int t = threadIdx.x;
  const int wv = t >> 6, lane = t & 63;
  const int k = blockIdx.y, k2 = C_ - 1 - k;
  const int be0 = blockIdx.x * 64;
  const int b = be0 / E_, e0 = be0 - b * E_;   // slices never straddle b (E_ % 64 == 0)
  const int ck = wv ? k2 : k;                  // chunk this wave stages AND emits
  // stage: 32 issues x (4 rows x 64 uints); LDS base wave-uniform, advancing 512 ushorts/issue
  {
    const unsigned short* g = (const unsigned short*)
        (CV + ((size_t)b * S_ + (size_t)ck * L_ + (lane >> 4)) * E_ + e0 + (lane & 15) * 4);
    unsigned short* lb = (unsigned short*)smU + wv * 16384;
#pragma unroll
    for (int j = 0; j < 32; ++j)
      async16(g + (size_t)j * 4 * E_ * 2, lb + j * 512);
  }
  asm volatile("s_waitcnt vmcnt(0)" ::: "memory");
  __syncthreads();
  const unsigned int* Da = smU + (size_t)wv * 8192;        // own chunk, ascending
  const unsigned int* Db = smU + (size_t)(1 - wv) * 8192;  // partner chunk, descending
  const int be = b * E_ + e0 + lane;
  float hf = HfIn[(size_t)ck * BE_ + be];
  float hb = HbIn[(size_t)(C_ - 1 - ck) * BE_ + be];
  unsigned short* hp = Hb + ((size_t)b * S_ + (size_t)ck * L_) * E_ + e0 + lane;
#pragma unroll 8
  for (int l = 0; l < L_; ++l) {
    const unsigned int pf = Da[l * 64 + lane];
    const unsigned int pb = Db[(L_ - 1 - l) * 64 + lane];
    hf = fmaf(h2f((unsigned short)pf), hf, h2f((unsigned short)(pf >> 16)));
    hb = fmaf(h2f((unsigned short)pb), hb, h2f((unsigned short)(pb >> 16)));
    hp[(size_t)l * E_] = f2b(hf + hb);
  }
}

// ---------- GEMM2 (proven structure: 256 thr, BK=64, async staging, T2 swizzle) ----------
// out[m,d] = sum_e H[m,e]*Wo[d,e].  tile 128m x 128d; 4 waves each 64m x 64d.
__global__ __launch_bounds__(256) void gemm2_mfma(const unsigned short* __restrict__ Hb,
                                                  const unsigned short* __restrict__ Wob,
                                                  float* __restrict__ Out) {
  __shared__ unsigned short lA[128 * 64];   // 16KB
  __shared__ unsigned short lB[128 * 64];   // 16KB
  const int t = threadIdx.x;
  const int m0 = blockIdx.x * 128;
  const int n0 = blockIdx.y * 128;
  const int wv = t >> 6, lane = t & 63;
  const int wm = wv >> 1, wn = wv & 1;
  const int lm = lane & 15, kg = lane >> 4;
  const int srow = lane >> 3;
  const int scs = (lane & 7) ^ srow;        // swizzled source 16B-column
  const bool stageA = (wv < 2);
  const unsigned short* gbase;
  if (stageA) gbase = Hb  + (size_t)(m0 + wv * 64 + srow) * E_ + scs * 8;
  else        gbase = Wob + (size_t)(n0 + (wv - 2) * 64 + srow) * E_ + scs * 8;
  unsigned short* lbase = (stageA ? lA : lB) + (size_t)(wv & 1) * 4096;

  const f32x4 z4 = {0.f, 0.f, 0.f, 0.f};
  f32x4 acc[4][4];
#pragma unroll
  for (int i = 0; i < 4; ++i)
#pragma unroll
    for (int j = 0; j < 4; ++j) acc[i][j] = z4;

  for (int k0 = 0; k0 < E_; k0 += 64) {
#pragma unroll
    for (int j = 0; j < 8; ++j)
      async16(gbase + k0 + (size_t)(j * 8) * E_, lbase + (size_t)j * 512);
    __syncthreads();
#pragma unroll
    for (int kh = 0; kh < 2; ++kh) {
      const int cb = ((((kh << 2) | kg) ^ (lm & 7)) << 3);   // swizzled col (ushort units)
      bf16x8 af[4], bfr[4];
#pragma unroll
      for (int mt = 0; mt < 4; ++mt)
        af[mt] = *(const bf16x8*)(lA + (size_t)(wm * 64 + mt * 16 + lm) * 64 + cb);
#pragma unroll
      for (int nt = 0; nt < 4; ++nt)
        bfr[nt] = *(const bf16x8*)(lB + (size_t)(wn * 64 + nt * 16 + lm) * 64 + cb);
#pragma unroll
      for (int mt = 0; mt < 4; ++mt)
#pragma unroll
        for (int nt = 0; nt < 4; ++nt)
          acc[mt][nt] = __builtin_amdgcn_mfma_f32_16x16x32_bf16(af[mt], bfr[nt], acc[mt][nt], 0, 0, 0);
    }
    __syncthreads();
  }
#pragma unroll
  for (int mt = 0; mt < 4; ++mt)
#pragma unroll
    for (int nt = 0; nt < 4; ++nt) {
      const int d = n0 + wn * 64 + nt * 16 + lm;
#pragma unroll
      for (int r = 0; r < 4; ++r) {
        const int m = m0 + wm * 64 + mt * 16 + kg * 4 + r;
        Out[(size_t)m * D_ + d] = acc[mt][nt][r];
      }
    }
}

extern "C" void kernel_launch(void* const* d_in, const int* in_sizes, int n_in,
                              void* d_out, int out_size, void* d_ws, size_t ws_size,
                              hipStream_t stream) {
  const float* x    = (const float*)d_in[0];
  const float* whg  = (const float*)d_in[1];
  const float* wout = (const float*)d_in[2];
  float* out = (float*)d_out;

  // ws (151 MB, proven-safe): [CV: M*E*4][H: M*E*2]
  unsigned int*  CV = (unsigned int*)d_ws;
  unsigned short* Hb = (unsigned short*)((char*)d_ws + (size_t)M_ * E_ * 4);
  unsigned short* Xb  = Hb;                     // bf16 X in H region until scan writes H
  unsigned short* Wb  = Xb + (size_t)M_ * D_;
  unsigned short* Wob = (unsigned short*)d_ws;  // bf16 W_out in CV region — ONLY after scans done
  // scan chunk scratch in d_out (gemm2 fully overwrites)
  float* P    = out;
  float* Qf   = out + (size_t)C_ * BE_;
  float* Qr   = out + 2 * (size_t)C_ * BE_;
  float* HfIn = out + 3 * (size_t)C_ * BE_;
  float* HbIn = out + 4 * (size_t)C_ * BE_;

  cvt_xw<<<NB_X + NB_WHG, 256, 0, stream>>>(x, Xb, whg, Wb);
  gemm1_mfma<<<dim3(M_ / 128, E_ / 64), 256, 0, stream>>>(Xb, Wb, CV, P, Qf, Qr);
  scan_p2<<<BE_ / 256, 256, 0, stream>>>(P, Qf, Qr, HfIn, HbIn);
  scan_p3<<<dim3(BE_ / 64, C_ / 2), 128, 0, stream>>>(CV, HfIn, HbIn, Hb);
  cvt_bf16<<<D_ * E_ / 1024, 256, 0, stream>>>(wout, Wob);   // CV dead now
  gemm2_mfma<<<dim3(M_ / 128, D_ / 128), 256, 0, stream>>>(Hb, Wob, out);
}